// Round 1
// baseline (253.416 us; speedup 1.0000x reference)
//
#include <hip/hip_runtime.h>
#include <math.h>

// Problem constants (setup_inputs is fixed: 1x3x2048x2048 fp32)
#define HH    2048
#define WW    2048
#define NCH   3
#define NOUT  2038          // 2048 - 10 (VALID 11-tap twice)
#define OWID  64            // output tile width per block
#define OHGT  24            // output tile height per block
#define IWID  74            // OWID + 10
#define IHGT  34            // OHGT + 10
#define SXW   76            // padded LDS stride (16B-aligned rows)
#define NTX   32            // ceil(2038/64)
#define NTY   85            // ceil(2038/24)
// total valid outputs: 3 * 2038 * 2038
#define NOUT_TOTAL 12460332.0f

__global__ __launch_bounds__(256, 2)
void ssim_main(const float* __restrict__ x, const float* __restrict__ y,
               float* __restrict__ acc) {
    __shared__ float sx[IHGT][SXW];
    __shared__ float sy[IHGT][SXW];
    __shared__ float hb[5][IHGT][OWID];   // h-blurred: mu1,mu2,xx,yy,xy
    __shared__ float wsum[4];

    const int tid = threadIdx.x;
    const int bx  = blockIdx.x;
    const int by  = blockIdx.y;
    const int ch  = blockIdx.z;
    const int gx0 = bx * OWID;
    const int gy0 = by * OHGT;
    const float* xb = x + (size_t)ch * HH * WW;
    const float* yb = y + (size_t)ch * HH * WW;

    // Gaussian weights (size 11, sigma 1.5), normalized — matches jnp f32
    float w[11];
    {
        float s = 0.f;
        #pragma unroll
        for (int i = 0; i < 11; ++i) {
            float d = (float)(i - 5);
            w[i] = expf(-d * d / 4.5f);
            s += w[i];
        }
        float inv = 1.f / s;
        #pragma unroll
        for (int i = 0; i < 11; ++i) w[i] *= inv;
    }

    // ---- Stage A: global -> LDS input tiles (edge-clamped; clamped values
    // only ever feed out-of-range outputs, which are guarded in stage C) ----
    for (int i = tid; i < IHGT * IWID; i += 256) {
        int r = i / IWID;
        int c = i - r * IWID;
        int gy = gy0 + r; if (gy > HH - 1) gy = HH - 1;
        int gx = gx0 + c; if (gx > WW - 1) gx = WW - 1;
        sx[r][c] = xb[gy * WW + gx];
        sy[r][c] = yb[gy * WW + gx];
    }
    __syncthreads();

    // ---- Stage B: horizontal blur of 5 quantities, 4 output cols per unit.
    // float4 LDS reads (16B-aligned thanks to SXW=76, c0%4==0). ----
    for (int u = tid; u < IHGT * (OWID / 4); u += 256) {
        int r  = u >> 4;          // u / 16
        int c0 = (u & 15) * 4;
        float4 x0 = *(const float4*)&sx[r][c0];
        float4 x1 = *(const float4*)&sx[r][c0 + 4];
        float4 x2 = *(const float4*)&sx[r][c0 + 8];
        float4 x3 = *(const float4*)&sx[r][c0 + 12];
        float4 y0 = *(const float4*)&sy[r][c0];
        float4 y1 = *(const float4*)&sy[r][c0 + 4];
        float4 y2 = *(const float4*)&sy[r][c0 + 8];
        float4 y3 = *(const float4*)&sy[r][c0 + 12];
        float xv[16] = {x0.x,x0.y,x0.z,x0.w, x1.x,x1.y,x1.z,x1.w,
                        x2.x,x2.y,x2.z,x2.w, x3.x,x3.y,x3.z,x3.w};
        float yv[16] = {y0.x,y0.y,y0.z,y0.w, y1.x,y1.y,y1.z,y1.w,
                        y2.x,y2.y,y2.z,y2.w, y3.x,y3.y,y3.z,y3.w};
        float xx[14], yy[14], xy[14];
        #pragma unroll
        for (int t = 0; t < 14; ++t) {
            xx[t] = xv[t] * xv[t];
            yy[t] = yv[t] * yv[t];
            xy[t] = xv[t] * yv[t];
        }
        float h1[4] = {0,0,0,0}, h2[4] = {0,0,0,0};
        float h11[4] = {0,0,0,0}, h22[4] = {0,0,0,0}, h12[4] = {0,0,0,0};
        #pragma unroll
        for (int k = 0; k < 11; ++k) {
            #pragma unroll
            for (int j = 0; j < 4; ++j) {
                h1[j]  = fmaf(w[k], xv[j + k], h1[j]);
                h2[j]  = fmaf(w[k], yv[j + k], h2[j]);
                h11[j] = fmaf(w[k], xx[j + k], h11[j]);
                h22[j] = fmaf(w[k], yy[j + k], h22[j]);
                h12[j] = fmaf(w[k], xy[j + k], h12[j]);
            }
        }
        *(float4*)&hb[0][r][c0] = make_float4(h1[0], h1[1], h1[2], h1[3]);
        *(float4*)&hb[1][r][c0] = make_float4(h2[0], h2[1], h2[2], h2[3]);
        *(float4*)&hb[2][r][c0] = make_float4(h11[0], h11[1], h11[2], h11[3]);
        *(float4*)&hb[3][r][c0] = make_float4(h22[0], h22[1], h22[2], h22[3]);
        *(float4*)&hb[4][r][c0] = make_float4(h12[0], h12[1], h12[2], h12[3]);
    }
    __syncthreads();

    // ---- Stage C: vertical blur via 16-row register window (6 outputs/thread)
    // + SSIM math + partial sum ----
    float partial = 0.f;
    {
        const int col = tid & 63;
        const int rg  = tid >> 6;     // 0..3
        const int r0  = rg * 6;       // rows r0..r0+5 of the 24-row tile
        float v1[16], v2[16], v11[16], v22[16], v12[16];
        #pragma unroll
        for (int j = 0; j < 16; ++j) {
            v1[j]  = hb[0][r0 + j][col];
            v2[j]  = hb[1][r0 + j][col];
            v11[j] = hb[2][r0 + j][col];
            v22[j] = hb[3][r0 + j][col];
            v12[j] = hb[4][r0 + j][col];
        }
        const float c1 = 1e-4f, c2 = 9e-4f;
        const int ocol = gx0 + col;
        #pragma unroll
        for (int i = 0; i < 6; ++i) {
            float mu1 = 0, mu2 = 0, b11 = 0, b22 = 0, b12 = 0;
            #pragma unroll
            for (int k = 0; k < 11; ++k) {
                mu1 = fmaf(w[k], v1[i + k], mu1);
                mu2 = fmaf(w[k], v2[i + k], mu2);
                b11 = fmaf(w[k], v11[i + k], b11);
                b22 = fmaf(w[k], v22[i + k], b22);
                b12 = fmaf(w[k], v12[i + k], b12);
            }
            int orow = gy0 + r0 + i;
            if (orow < NOUT && ocol < NOUT) {
                float mu1sq = mu1 * mu1;
                float mu2sq = mu2 * mu2;
                float mu12  = mu1 * mu2;
                float s11 = b11 - mu1sq;
                float s22 = b22 - mu2sq;
                float s12 = b12 - mu12;
                float csn = 2.f * s12 + c2;
                float csd = s11 + s22 + c2;
                float ln  = 2.f * mu12 + c1;
                float ld  = mu1sq + mu2sq + c1;
                partial += (csn * ln) / (csd * ld);
            }
        }
    }

    // ---- Reduction: wave shuffle -> block -> one atomic per block ----
    #pragma unroll
    for (int off = 32; off > 0; off >>= 1)
        partial += __shfl_down(partial, off, 64);
    if ((tid & 63) == 0) wsum[tid >> 6] = partial;
    __syncthreads();
    if (tid == 0) {
        float s = wsum[0] + wsum[1] + wsum[2] + wsum[3];
        atomicAdd(acc, s);
    }
}

__global__ void ssim_finalize(const float* __restrict__ acc,
                              float* __restrict__ out) {
    out[0] = 1.f - acc[0] / NOUT_TOTAL;
}

extern "C" void kernel_launch(void* const* d_in, const int* in_sizes, int n_in,
                              void* d_out, int out_size, void* d_ws, size_t ws_size,
                              hipStream_t stream) {
    const float* x = (const float*)d_in[0];
    const float* y = (const float*)d_in[1];
    float* out = (float*)d_out;
    float* acc = (float*)d_ws;

    // d_ws is re-poisoned (0xAA) before every launch — zero the accumulator.
    hipMemsetAsync(acc, 0, sizeof(float), stream);

    dim3 grid(NTX, NTY, NCH);
    ssim_main<<<grid, dim3(256), 0, stream>>>(x, y, acc);
    ssim_finalize<<<1, 1, 0, stream>>>(acc, out);
}